// Round 9
// baseline (42.189 us; speedup 1.0000x reference)
//
#include <hip/hip_runtime.h>

// Separable 3x3 window: w = outer(v,v), v = [A_W, B_W, A_W]
#define A_W 0.30780133f
#define B_W 0.38439735f

#define IMG_W 512
#define CROP_LO 5
#define CROP_HI 507          // exclusive; rows/cols 5..506 kept (502 each)
#define STRIP 4              // output rows per thread
#define NSTRIPS 126          // ceil(502/4); last strip's rows 507+ masked
#define BT 256

// Per-row horizontal sums for the thread's 2 owned columns.
struct H10 { float a1[2], a2[2], a11[2], a22[2], a12[2]; };

__device__ __forceinline__ void hsum(const float4& x, const float4& y, H10& h) {
    float xx0 = x.x * x.x, xx1 = x.y * x.y, xx2 = x.z * x.z, xx3 = x.w * x.w;
    float yy0 = y.x * y.x, yy1 = y.y * y.y, yy2 = y.z * y.z, yy3 = y.w * y.w;
    float xy0 = x.x * y.x, xy1 = x.y * y.y, xy2 = x.z * y.z, xy3 = x.w * y.w;
    h.a1[0]  = A_W * (x.x + x.z) + B_W * x.y;
    h.a1[1]  = A_W * (x.y + x.w) + B_W * x.z;
    h.a2[0]  = A_W * (y.x + y.z) + B_W * y.y;
    h.a2[1]  = A_W * (y.y + y.w) + B_W * y.z;
    h.a11[0] = A_W * (xx0 + xx2) + B_W * xx1;
    h.a11[1] = A_W * (xx1 + xx3) + B_W * xx2;
    h.a22[0] = A_W * (yy0 + yy2) + B_W * yy1;
    h.a22[1] = A_W * (yy1 + yy3) + B_W * yy2;
    h.a12[0] = A_W * (xy0 + xy2) + B_W * xy1;
    h.a12[1] = A_W * (xy1 + xy3) + B_W * xy2;
}

__global__ __launch_bounds__(BT, 4) void ssim_loss_main(
    const float* __restrict__ X, const float* __restrict__ Y,
    float* __restrict__ partials) {
    const int t  = threadIdx.x;
    const int c0 = 4 + 2 * t;              // owned cols c0, c0+1
    const int lc = min(c0, 508) - 1;       // float4 window base [lc..lc+3]
    const int b  = blockIdx.y;
    const int r0 = CROP_LO + STRIP * blockIdx.x;   // 5..505

    const float* Xb = X + (size_t)b * IMG_W * IMG_W;
    const float* Yb = Y + (size_t)b * IMG_W * IMG_W;

    const float cm0 = (c0     >= CROP_LO && c0     < CROP_HI) ? 1.0f : 0.0f;
    const float cm1 = (c0 + 1 >= CROP_LO && c0 + 1 < CROP_HI) ? 1.0f : 0.0f;

    // ---- Batch-load phase: 12 independent float4 loads, all in flight ----
    // Rows r0-1 .. r0+4 (range 4..509, always in-bounds), both images.
    float4 xr[STRIP + 2], yr[STRIP + 2];
#pragma unroll
    for (int r = 0; r < STRIP + 2; ++r) {
        const size_t off = (size_t)(r0 - 1 + r) * IMG_W + lc;
        xr[r] = *(const float4*)(Xb + off);
        yr[r] = *(const float4*)(Yb + off);
    }
    // Pin the batch: nothing (esp. these loads) may be reordered across this.
    __builtin_amdgcn_sched_barrier(0);

    // ---- Compute phase: sliding 3-row window over the 6 register rows ----
    H10 P, C, N;
    hsum(xr[0], yr[0], P);
    hsum(xr[1], yr[1], C);

    float acc = 0.0f;
#pragma unroll
    for (int rr = 0; rr < STRIP; ++rr) {
        hsum(xr[rr + 2], yr[rr + 2], N);
        float racc = 0.0f;
#pragma unroll
        for (int k = 0; k < 2; ++k) {
            float s1  = A_W * (P.a1[k]  + N.a1[k])  + B_W * C.a1[k];
            float s2  = A_W * (P.a2[k]  + N.a2[k])  + B_W * C.a2[k];
            float s11 = A_W * (P.a11[k] + N.a11[k]) + B_W * C.a11[k];
            float s22 = A_W * (P.a22[k] + N.a22[k]) + B_W * C.a22[k];
            float s12 = A_W * (P.a12[k] + N.a12[k]) + B_W * C.a12[k];
            float v1 = s11 - s1 * s1;      // sigma1_sq
            float v2 = s22 - s2 * s2;      // sigma2_sq
            float cv = s12 - s1 * s2;      // sigma12
            racc += (k ? cm1 : cm0) * (v1 * v2 - 2.0f * cv);
        }
        acc += (r0 + rr < CROP_HI) ? racc : 0.0f;   // row mask (tail strip)
        P = C; C = N;
    }

    // ---- Block reduction: 4 waves ----
    for (int off = 32; off > 0; off >>= 1) acc += __shfl_down(acc, off, 64);
    __shared__ float wsum[BT / 64];
    if ((t & 63) == 0) wsum[t >> 6] = acc;
    __syncthreads();
    if (t == 0)
        partials[blockIdx.x + NSTRIPS * b] = wsum[0] + wsum[1] + wsum[2] + wsum[3];
}

__global__ __launch_bounds__(256) void ssim_loss_finalize(
    const float* __restrict__ partials, int n, float* __restrict__ out) {
    const int tid = threadIdx.x;
    float s = 0.0f;
    for (int i = tid; i < n; i += 256) s += partials[i];
    for (int off = 32; off > 0; off >>= 1) s += __shfl_down(s, off, 64);
    __shared__ float wsum[4];
    if ((tid & 63) == 0) wsum[tid >> 6] = s;
    __syncthreads();
    if (tid == 0) {
        float total = wsum[0] + wsum[1] + wsum[2] + wsum[3];
        out[0] = total * (1.0f / 252004.0f);   // mean over 502*502, summed over batch
    }
}

extern "C" void kernel_launch(void* const* d_in, const int* in_sizes, int n_in,
                              void* d_out, int out_size, void* d_ws, size_t ws_size,
                              hipStream_t stream) {
    const float* X = (const float*)d_in[0];
    const float* Y = (const float*)d_in[1];
    float* out = (float*)d_out;
    float* partials = (float*)d_ws;   // NSTRIPS*64 = 8064 floats

    dim3 grid(NSTRIPS, 64);
    ssim_loss_main<<<grid, BT, 0, stream>>>(X, Y, partials);
    ssim_loss_finalize<<<1, 256, 0, stream>>>(partials, NSTRIPS * 64, out);
}

// Round 10
// 29.815 us; speedup vs baseline: 1.4151x; 1.4151x over previous
//
#include <hip/hip_runtime.h>

// Separable 3x3 window: w = outer(v,v), v = [A_W, B_W, A_W]
#define A_W 0.30780133f
#define B_W 0.38439735f

#define IMG_W 512
#define CROP_LO 5
#define CROP_HI 507          // exclusive; rows/cols 5..506 kept (502 each)
#define STRIP 16
#define NSTRIPS 32
#define BT 256

// Per-row horizontal sums for the thread's 2 owned columns.
struct H10 { float a1[2], a2[2], a11[2], a22[2], a12[2]; };

__device__ __forceinline__ void hsum(const float4& x, const float4& y, H10& h) {
    float xx0 = x.x * x.x, xx1 = x.y * x.y, xx2 = x.z * x.z, xx3 = x.w * x.w;
    float yy0 = y.x * y.x, yy1 = y.y * y.y, yy2 = y.z * y.z, yy3 = y.w * y.w;
    float xy0 = x.x * y.x, xy1 = x.y * y.y, xy2 = x.z * y.z, xy3 = x.w * y.w;
    h.a1[0]  = A_W * (x.x + x.z) + B_W * x.y;
    h.a1[1]  = A_W * (x.y + x.w) + B_W * x.z;
    h.a2[0]  = A_W * (y.x + y.z) + B_W * y.y;
    h.a2[1]  = A_W * (y.y + y.w) + B_W * y.z;
    h.a11[0] = A_W * (xx0 + xx2) + B_W * xx1;
    h.a11[1] = A_W * (xx1 + xx3) + B_W * xx2;
    h.a22[0] = A_W * (yy0 + yy2) + B_W * yy1;
    h.a22[1] = A_W * (yy1 + yy3) + B_W * yy2;
    h.a12[0] = A_W * (xy0 + xy2) + B_W * xy1;
    h.a12[1] = A_W * (xy1 + xy3) + B_W * xy2;
}

// Compiler-proof async load: issue order preserved, dest regs pinned live.
#define GLOAD(dst, ptr) \
    asm volatile("global_load_dwordx4 %0, %1, off" : "=v"(dst) : "v"(ptr))
// Counted drain + scheduler fence (rule #18: VALU can hoist past bare waitcnt).
#define WAITCNT(N)                                              \
    asm volatile("s_waitcnt vmcnt(" #N ")" ::: "memory");       \
    __builtin_amdgcn_sched_barrier(0)

__global__ __launch_bounds__(BT, 4) void ssim_loss_main(
    const float* __restrict__ X, const float* __restrict__ Y,
    float* __restrict__ partials) {
    const int t  = threadIdx.x;
    const int c0 = 4 + 2 * t;              // owned cols c0, c0+1
    const int lc = min(c0, 508) - 1;       // float4 window base [lc..lc+3]
    const int b  = blockIdx.y;
    const int r0 = CROP_LO + STRIP * blockIdx.x;   // 5..501

    const float* Xb = X + (size_t)b * IMG_W * IMG_W;
    const float* Yb = Y + (size_t)b * IMG_W * IMG_W;

    const float cm0 = (c0     >= CROP_LO && c0     < CROP_HI) ? 1.0f : 0.0f;
    const float cm1 = (c0 + 1 >= CROP_LO && c0 + 1 < CROP_HI) ? 1.0f : 0.0f;

    auto adrX = [&](int row) { return Xb + (size_t)min(row, IMG_W - 1) * IMG_W + lc; };
    auto adrY = [&](int row) { return Yb + (size_t)min(row, IMG_W - 1) * IMG_W + lc; };

    // ---- Prologue: 12 loads in flight before first use ----
    float4 px0, py0, px1, py1;
    GLOAD(px0, adrX(r0 - 1)); GLOAD(py0, adrY(r0 - 1));
    GLOAD(px1, adrX(r0));     GLOAD(py1, adrY(r0));

    float4 bx[2][4], by[2][4];             // double-buffered 4-row batches
#pragma unroll
    for (int rr = 0; rr < 4; ++rr) {       // batch 0: rows r0+1 .. r0+4
        GLOAD(bx[0][rr], adrX(r0 + 1 + rr));
        GLOAD(by[0][rr], adrY(r0 + 1 + rr));
    }
    WAITCNT(8);                            // prologue 4 done; batch0 in flight

    H10 P, C, N;
    hsum(px0, py0, P);
    hsum(px1, py1, C);

    float acc = 0.0f;
#pragma unroll
    for (int g = 0; g < 4; ++g) {          // 4 groups x 4 output rows
        if (g < 3) {                       // issue next batch: rows r0+4g+5..+8
#pragma unroll
            for (int rr = 0; rr < 4; ++rr) {
                GLOAD(bx[(g + 1) & 1][rr], adrX(r0 + 4 * g + 5 + rr));
                GLOAD(by[(g + 1) & 1][rr], adrY(r0 + 4 * g + 5 + rr));
            }
            WAITCNT(8);                    // batch g complete, g+1 in flight
        } else {
            WAITCNT(0);                    // last batch: drain fully
        }
#pragma unroll
        for (int rr = 0; rr < 4; ++rr) {
            hsum(bx[g & 1][rr], by[g & 1][rr], N);
            float racc = 0.0f;
#pragma unroll
            for (int k = 0; k < 2; ++k) {
                float s1  = A_W * (P.a1[k]  + N.a1[k])  + B_W * C.a1[k];
                float s2  = A_W * (P.a2[k]  + N.a2[k])  + B_W * C.a2[k];
                float s11 = A_W * (P.a11[k] + N.a11[k]) + B_W * C.a11[k];
                float s22 = A_W * (P.a22[k] + N.a22[k]) + B_W * C.a22[k];
                float s12 = A_W * (P.a12[k] + N.a12[k]) + B_W * C.a12[k];
                float v1 = s11 - s1 * s1;      // sigma1_sq
                float v2 = s22 - s2 * s2;      // sigma2_sq
                float cv = s12 - s1 * s2;      // sigma12
                racc += (k ? cm1 : cm0) * (v1 * v2 - 2.0f * cv);
            }
            acc += (r0 + 4 * g + rr < CROP_HI) ? racc : 0.0f;
            P = C; C = N;
        }
    }

    // ---- Block reduction: 4 waves ----
    for (int off = 32; off > 0; off >>= 1) acc += __shfl_down(acc, off, 64);
    __shared__ float wsum[BT / 64];
    if ((t & 63) == 0) wsum[t >> 6] = acc;
    __syncthreads();
    if (t == 0)
        partials[blockIdx.x + NSTRIPS * b] = wsum[0] + wsum[1] + wsum[2] + wsum[3];
}

__global__ __launch_bounds__(256) void ssim_loss_finalize(
    const float* __restrict__ partials, int n, float* __restrict__ out) {
    const int tid = threadIdx.x;
    float s = 0.0f;
    for (int i = tid; i < n; i += 256) s += partials[i];
    for (int off = 32; off > 0; off >>= 1) s += __shfl_down(s, off, 64);
    __shared__ float wsum[4];
    if ((tid & 63) == 0) wsum[tid >> 6] = s;
    __syncthreads();
    if (tid == 0) {
        float total = wsum[0] + wsum[1] + wsum[2] + wsum[3];
        out[0] = total * (1.0f / 252004.0f);   // mean over 502*502, summed over batch
    }
}

extern "C" void kernel_launch(void* const* d_in, const int* in_sizes, int n_in,
                              void* d_out, int out_size, void* d_ws, size_t ws_size,
                              hipStream_t stream) {
    const float* X = (const float*)d_in[0];
    const float* Y = (const float*)d_in[1];
    float* out = (float*)d_out;
    float* partials = (float*)d_ws;   // NSTRIPS*64 = 2048 floats

    dim3 grid(NSTRIPS, 64);
    ssim_loss_main<<<grid, BT, 0, stream>>>(X, Y, partials);
    ssim_loss_finalize<<<1, 256, 0, stream>>>(partials, NSTRIPS * 64, out);
}